// Round 2
// baseline (7723.564 us; speedup 1.0000x reference)
//
#include <hip/hip_runtime.h>
#include <stdint.h>
#include <stddef.h>

#define T_STEPS 1024
#define BATCH   512
#define HID     256
#define DIN     64

typedef __attribute__((ext_vector_type(8))) short short8;
typedef __attribute__((ext_vector_type(4))) short short4v;
typedef __attribute__((ext_vector_type(2))) short short2v;
typedef __attribute__((ext_vector_type(4))) float float4v;
typedef __attribute__((ext_vector_type(4))) unsigned int uint4v;

static __device__ __forceinline__ short f2bf(float f) {
  union { float f; unsigned u; } v; v.f = f;
  unsigned r = (v.u + 0x7FFFu + ((v.u >> 16) & 1u)) >> 16;
  return (short)r;
}
static __device__ __forceinline__ float sigm(float x) {
  return 1.0f / (1.0f + __expf(-x));
}
static __device__ __forceinline__ float tanh_f(float x) {
  return 2.0f / (1.0f + __expf(-2.0f * x)) - 1.0f;
}

// ---------------------------------------------------------------------------
// Same-XCD L2 exchange ops. sc0 bypasses the CU L1; loads/stores meet at the
// XCD-shared L2 instead of the MALL coherence point. Only tried between
// blocks CONFIRMED on the same XCD; always backed by the MALL slow path.
// ---------------------------------------------------------------------------
static __device__ __forceinline__ void st16_sc0(float* p, uint4v v) {
  asm volatile("global_store_dwordx4 %0, %1, off sc0" :: "v"(p), "v"(v) : "memory");
}
static __device__ __forceinline__ uint4v ld16_sc0(const float* p) {
  uint4v r;
  asm volatile("global_load_dwordx4 %0, %1, off sc0\n\ts_waitcnt vmcnt(0)"
               : "=v"(r) : "v"(p) : "memory");
  return r;
}

// ---------------------------------------------------------------------------
// Persistent LSTM recurrence. 64 blocks = 32 batch-groups x 2 gate-halves.
// Pair exchange of h(t) per thread = 4 hidden values.
//   FAST word (16B, sc0 / same-XCD L2): [id | bf16x2 | bf16x2 | id], where
//     id = 0xC0DE0000|t (exact step, not parity). Payload is the EXACT bf16
//     the producer writes to its own A-LDS -> zero numeric divergence.
//     Poison 0xAAAAAAAA and clear 0 never match an id; duplicated id at both
//     ends rejects any torn 8B-half observation; exact ids cannot alias
//     across steps. Consumer polls 128x then falls back to the slow path.
//   SLOW words (2x8B, agent-scope MALL atomics): unchanged baseline protocol
//     (fp32 words self-tagged in mantissa bit0 with step parity) — proven
//     correct; producer ALWAYS publishes both (dual-publish), so fallback is
//     always available and correctness never depends on the fast path.
// Freshness: prep_kernel zeroes the XCD table every launch (stream order).
// ---------------------------------------------------------------------------
__global__ __launch_bounds__(512, 2) void lstm_kernel(
    const float* __restrict__ x, const float* __restrict__ h0,
    const float* __restrict__ c0, const float* __restrict__ W_ih,
    const float* __restrict__ W_hh, const float* __restrict__ b_ih,
    const float* __restrict__ b_hh, float* __restrict__ exch,
    float* __restrict__ exchf, unsigned* __restrict__ tbl,
    uint16_t* __restrict__ hs) {
  const int tid   = threadIdx.x;
  const int blk   = blockIdx.x;
  const int group = blk & 31;
  const int half  = blk >> 5;
  const int b0    = group * 16;
  const int w     = tid >> 6;
  const int lane  = tid & 63;
  const int quad  = lane >> 4;
  const int l16   = lane & 15;
  const int partner = blk ^ 32;

  __shared__ short Alds[16 * 328];   // A = [h(256) | x(64)] bf16
  __shared__ float Glds[16 * 516];   // gate preacts fp32
  __shared__ int s_fastex;

  // ---- update-phase mapping: thread owns (urow, hh0..hh0+3) of its half
  const int urow = tid >> 5;
  const int hh0  = (tid & 31) * 4;
  const int xc   = (tid & 31) * 2;

  // exchange word pointers. widx in u64 units (slow) / 16B slots (fast).
  const int widx = urow * 64 + (hh0 >> 1);
  unsigned long long* sbuf[2];
  const unsigned long long* pbuf[2];
  float* sfast[2];
  const float* pfast[2];
#pragma unroll
  for (int bfi = 0; bfi < 2; ++bfi) {
    sbuf[bfi]  = (unsigned long long*)(exch + ((size_t)blk * 2 + bfi) * 2048) + widx;
    pbuf[bfi]  = (const unsigned long long*)(exch + ((size_t)partner * 2 + bfi) * 2048) + widx;
    sfast[bfi] = exchf + ((size_t)blk * 2 + bfi) * 2048 + (widx << 1);
    pfast[bfi] = exchf + ((size_t)partner * 2 + bfi) * 2048 + (widx << 1);
  }

  // ---- clear OWN fast buffers (id dword -> 0, never accepted) before
  // publishing our XCD; barrier drains vmcnt so clears are in L2 first.
  {
    uint4v z; z[0] = 0u; z[1] = 0u; z[2] = 0u; z[3] = 0u;
    st16_sc0(sfast[0], z);
    st16_sc0(sfast[1], z);
  }
  __syncthreads();
  if (tid == 0) {
    int xcd;
    asm volatile("s_getreg_b32 %0, hwreg(HW_REG_XCC_ID)" : "=s"(xcd));
    unsigned my = 0x5AB00000u | ((unsigned)xcd & 0xFFu);
    __hip_atomic_store(&tbl[blk], my, __ATOMIC_RELAXED, __HIP_MEMORY_SCOPE_AGENT);
    unsigned pv = 0;
    for (int g2 = 0; g2 < (1 << 16); ++g2) {
      pv = __hip_atomic_load(&tbl[partner], __ATOMIC_RELAXED, __HIP_MEMORY_SCOPE_AGENT);
      if ((pv & 0xFFFFFF00u) == 0x5AB00000u) break;
      __builtin_amdgcn_s_sleep(8);
    }
    s_fastex = (((pv & 0xFFFFFF00u) == 0x5AB00000u) &&
                ((pv & 0xFFu) == (my & 0xFFu))) ? 1 : 0;
  }

  // ---- resident weights, PERMUTED by half so register indices are static:
  // bw[0..3] = own-half h K-tiles, bw[4..7] = partner-half, bw[8..9] = x.
  short8 bw[10][4];
#pragma unroll
  for (int j = 0; j < 10; ++j) {
    int ktA = (j < 4) ? (half * 4 + j) : (j < 8) ? ((1 - half) * 4 + (j - 4)) : j;
#pragma unroll
    for (int nt = 0; nt < 4; ++nt) {
      int n_loc = w * 64 + nt * 16 + l16;          // 0..511 within block
      int gate  = n_loc >> 7;
      int hh    = n_loc & 127;
      int grow  = gate * 256 + half * 128 + hh;    // output row in 4H
      const float* src = (ktA < 8)
          ? (W_hh + (size_t)grow * 256 + ktA * 32 + quad * 8)
          : (W_ih + (size_t)grow * 64 + (ktA - 8) * 32 + quad * 8);
      short8 bv;
#pragma unroll
      for (int e = 0; e < 8; ++e) bv[e] = f2bf(src[e]);
      bw[j][nt] = bv;
    }
  }

  float bias[4][4];
  float c_reg[4];
#pragma unroll
  for (int g = 0; g < 4; ++g) {
    const float* bi = b_ih + g * 256 + half * 128 + hh0;
    const float* bh = b_hh + g * 256 + half * 128 + hh0;
#pragma unroll
    for (int r = 0; r < 4; ++r) bias[g][r] = bi[r] + bh[r];
  }
  {
    const float* c0p = c0 + (size_t)(b0 + urow) * 256 + half * 128 + hh0;
#pragma unroll
    for (int r = 0; r < 4; ++r) c_reg[r] = c0p[r];
  }

  // ---- init A-LDS: full h0 + x(0)
  {
    int c8 = (tid & 31) * 8;
    const float* hp = h0 + (size_t)(b0 + urow) * 256 + c8;
    short8 hv;
#pragma unroll
    for (int e = 0; e < 8; ++e) hv[e] = f2bf(hp[e]);
    *(short8*)&Alds[urow * 328 + c8] = hv;
    const float* xp = x + ((size_t)(b0 + urow) * T_STEPS + 0) * DIN + xc;
    short2v xv2; xv2[0] = f2bf(xp[0]); xv2[1] = f2bf(xp[1]);
    *(short2v*)&Alds[urow * 328 + 256 + xc] = xv2;
  }
  __syncthreads();
  const int fastex = s_fastex;

  const int ownbase = half * 128;
  const int pbase   = (1 - half) * 128;

  for (int t = 0; t < T_STEPS; ++t) {
    // ---- phase 1: own-half h tiles + x tiles (no exchange needed)
    float4v acc[4] = {{0.f,0.f,0.f,0.f},{0.f,0.f,0.f,0.f},
                      {0.f,0.f,0.f,0.f},{0.f,0.f,0.f,0.f}};
    int tn = (t + 1 < T_STEPS) ? (t + 1) : t;
    const float* xp = x + ((size_t)(b0 + urow) * T_STEPS + tn) * DIN + xc;
    float xa = xp[0], xb = xp[1];

#pragma unroll
    for (int j = 0; j < 4; ++j) {
      short8 a = *(const short8*)&Alds[l16 * 328 + ownbase + j * 32 + quad * 8];
#pragma unroll
      for (int nt = 0; nt < 4; ++nt)
        acc[nt] = __builtin_amdgcn_mfma_f32_16x16x32_bf16(a, bw[j][nt], acc[nt], 0, 0, 0);
    }
#pragma unroll
    for (int j = 8; j < 10; ++j) {
      short8 a = *(const short8*)&Alds[l16 * 328 + 256 + (j - 8) * 32 + quad * 8];
#pragma unroll
      for (int nt = 0; nt < 4; ++nt)
        acc[nt] = __builtin_amdgcn_mfma_f32_16x16x32_bf16(a, bw[j][nt], acc[nt], 0, 0, 0);
    }

    // ---- obtain partner's h(t-1) words (overlapped with phase 1):
    // try fast (same-XCD L2, exact step-id) then fall back to slow (MALL).
    if (t > 0) {
      int buf = (t - 1) & 1;
      short4v pv4;
      bool got = false;
      if (fastex) {
        unsigned expect = 0xC0DE0000u + (unsigned)(t - 1);
        for (int g2 = 0; g2 < 128; ++g2) {
          uint4v v = ld16_sc0(pfast[buf]);
          if (v[0] == expect && v[3] == expect) {
            pv4[0] = (short)(v[1] & 0xFFFFu); pv4[1] = (short)(v[1] >> 16);
            pv4[2] = (short)(v[2] & 0xFFFFu); pv4[3] = (short)(v[2] >> 16);
            got = true;
            break;
          }
        }
      }
      if (!got) {
        unsigned tag = 1u ^ (((unsigned)(t - 1) >> 1) & 1u);
        const unsigned long long* p = pbuf[buf];
        unsigned long long w0, w1;
        int guard = 0;
        for (;;) {
          w0 = __hip_atomic_load(p,     __ATOMIC_RELAXED, __HIP_MEMORY_SCOPE_AGENT);
          w1 = __hip_atomic_load(p + 1, __ATOMIC_RELAXED, __HIP_MEMORY_SCOPE_AGENT);
          bool ok = (((unsigned)w0 & 1u) == tag) & ((((unsigned)(w0 >> 32)) & 1u) == tag) &
                    (((unsigned)w1 & 1u) == tag) & ((((unsigned)(w1 >> 32)) & 1u) == tag);
          if (ok) break;
          if (++guard > 4096) break;   // bounded: bug -> absmax fail, not hang
        }
        union { unsigned u; float f; } g0, g1, g2, g3;
        g0.u = (unsigned)w0; g1.u = (unsigned)(w0 >> 32);
        g2.u = (unsigned)w1; g3.u = (unsigned)(w1 >> 32);
        pv4[0] = f2bf(g0.f); pv4[1] = f2bf(g1.f);
        pv4[2] = f2bf(g2.f); pv4[3] = f2bf(g3.f);
      }
      *(short4v*)&Alds[urow * 328 + pbase + hh0] = pv4;
    }
    __syncthreads();   // partner region ready

    // ---- phase 2: partner-half h tiles
#pragma unroll
    for (int j = 4; j < 8; ++j) {
      short8 a = *(const short8*)&Alds[l16 * 328 + pbase + (j - 4) * 32 + quad * 8];
#pragma unroll
      for (int nt = 0; nt < 4; ++nt)
        acc[nt] = __builtin_amdgcn_mfma_f32_16x16x32_bf16(a, bw[j][nt], acc[nt], 0, 0, 0);
    }
    // preacts -> G-LDS (D layout: col=l16, row=quad*4+r)
#pragma unroll
    for (int nt = 0; nt < 4; ++nt) {
      int col = w * 64 + nt * 16 + l16;
#pragma unroll
      for (int r = 0; r < 4; ++r)
        Glds[(quad * 4 + r) * 516 + col] = acc[nt][r];
    }
    __syncthreads();   // gates ready; A-LDS reads done

    // ---- cell update (fp32 state in regs)
    float4v ip = *(const float4v*)&Glds[urow * 516 + 0   + hh0];
    float4v fp = *(const float4v*)&Glds[urow * 516 + 128 + hh0];
    float4v gp = *(const float4v*)&Glds[urow * 516 + 256 + hh0];
    float4v op = *(const float4v*)&Glds[urow * 516 + 384 + hh0];
    float hf[4];
    short hb[4];
#pragma unroll
    for (int r = 0; r < 4; ++r) {
      float iv = sigm(ip[r] + bias[0][r]);
      float fv = sigm(fp[r] + bias[1][r]);
      float gv = tanh_f(gp[r] + bias[2][r]);
      float ov = sigm(op[r] + bias[3][r]);
      float cv = fv * c_reg[r] + iv * gv;
      c_reg[r] = cv;
      hf[r] = ov * tanh_f(cv);
      hb[r] = f2bf(hf[r]);
    }
    // dual-publish exchange store FIRST (earliest visibility to partner)
    {
      int buf = t & 1;
      // fast word: exact bf16 payload + duplicated exact step-id
      if (fastex) {
        unsigned idw = 0xC0DE0000u + (unsigned)t;
        unsigned pay01 = (unsigned)(unsigned short)hb[0]
                       | ((unsigned)(unsigned short)hb[1] << 16);
        unsigned pay23 = (unsigned)(unsigned short)hb[2]
                       | ((unsigned)(unsigned short)hb[3] << 16);
        uint4v sv; sv[0] = idw; sv[1] = pay01; sv[2] = pay23; sv[3] = idw;
        st16_sc0(sfast[buf], sv);
      }
      // slow words: baseline self-tagged fp32 (always, fallback safety net)
      unsigned tag = 1u ^ (((unsigned)t >> 1) & 1u);
      union { float f; unsigned u; } u0, u1, u2, u3;
      u0.f = hf[0]; u1.f = hf[1]; u2.f = hf[2]; u3.f = hf[3];
      unsigned long long w0 = (unsigned long long)((u0.u & ~1u) | tag)
                            | ((unsigned long long)((u1.u & ~1u) | tag) << 32);
      unsigned long long w1 = (unsigned long long)((u2.u & ~1u) | tag)
                            | ((unsigned long long)((u3.u & ~1u) | tag) << 32);
      __hip_atomic_store(sbuf[buf],     w0, __ATOMIC_RELAXED, __HIP_MEMORY_SCOPE_AGENT);
      __hip_atomic_store(sbuf[buf] + 1, w1, __ATOMIC_RELAXED, __HIP_MEMORY_SCOPE_AGENT);
    }
    // own half -> A-LDS
    short4v hv4; hv4[0] = hb[0]; hv4[1] = hb[1]; hv4[2] = hb[2]; hv4[3] = hb[3];
    *(short4v*)&Alds[urow * 328 + ownbase + hh0] = hv4;
    // hs for MLP: plain cached store (kernel boundary provides visibility)
    *(short4v*)(hs + ((size_t)(b0 + urow) * T_STEPS + t) * HID + ownbase + hh0) = hv4;
    // x(t+1) -> A-LDS
    short2v xv2; xv2[0] = f2bf(xa); xv2[1] = f2bf(xb);
    *(short2v*)&Alds[urow * 328 + 256 + xc] = xv2;
    __syncthreads();   // own half + x ready for next phase 1
  }
}

// ---------------------------------------------------------------------------
// One-time fp32 -> bf16 conversion of MLP weights into workspace, plus
// zeroing of the XCD pairing table (fresh, poison-proof table every launch
// via stream ordering).
// ---------------------------------------------------------------------------
__global__ void prep_kernel(const float* __restrict__ W1, const float* __restrict__ W2,
                            short* __restrict__ W1b, short* __restrict__ W2b,
                            unsigned* __restrict__ tbl) {
  int i = blockIdx.x * 512 + threadIdx.x;   // 160*512 = 81920 = 65536 + 16384
  if (i < 64)
    __hip_atomic_store(&tbl[i], 0u, __ATOMIC_RELAXED, __HIP_MEMORY_SCOPE_AGENT);
  if (i < 65536) W1b[i] = f2bf(W1[i]);
  else           W2b[i - 65536] = f2bf(W2[i - 65536]);
}

// ---------------------------------------------------------------------------
// Fused MLP head: y = relu(hs @ W1^T + b1) @ W2^T + b2, * mask.
// 4096 blocks x 128 rows (weights amortized over 2x more rows than R1,
// and loaded as bf16 -> 4x less weight traffic per row).
// ---------------------------------------------------------------------------
__global__ __launch_bounds__(512, 2) void mlp_kernel(
    const uint16_t* __restrict__ hs, const short* __restrict__ W1b,
    const float* __restrict__ b1, const short* __restrict__ W2b,
    const float* __restrict__ b2, const float* __restrict__ mask,
    float* __restrict__ y) {
  const int tid   = threadIdx.x;
  const int rows0 = blockIdx.x * 128;
  const int w     = tid >> 6;
  const int lane  = tid & 63;
  const int quad  = lane >> 4;
  const int l16   = lane & 15;

  __shared__ short S[128 * 264];  // h tile, later aliased as act tile

  // stage h tile [128,256] bf16
#pragma unroll
  for (int kk = 0; kk < 8; ++kk) {
    int c   = tid + kk * 512;
    int row = c >> 5;
    int off = (c & 31) * 8;
    *(short8*)&S[row * 264 + off] =
        *(const short8*)(hs + (size_t)(rows0 + row) * HID + off);
  }

  // W1 B-fragments; wave w owns hidden cols [w*32, w*32+32)
  short8 bf1[2][8];
  float  b1v[2];
#pragma unroll
  for (int nt = 0; nt < 2; ++nt) {
    int n = w * 32 + nt * 16 + l16;
    b1v[nt] = b1[n];
#pragma unroll
    for (int kt = 0; kt < 8; ++kt)
      bf1[nt][kt] = *(const short8*)(W1b + (size_t)n * 256 + kt * 32 + quad * 8);
  }
  __syncthreads();

  // GEMM1: act = relu(h @ W1^T + b1), 8 M-tiles
  float4v acc1[2][8];
#pragma unroll
  for (int nt = 0; nt < 2; ++nt)
#pragma unroll
    for (int mt = 0; mt < 8; ++mt) acc1[nt][mt] = (float4v){0.f,0.f,0.f,0.f};
#pragma unroll
  for (int kt = 0; kt < 8; ++kt) {
#pragma unroll
    for (int mt = 0; mt < 8; ++mt) {
      short8 a = *(const short8*)&S[(mt * 16 + l16) * 264 + kt * 32 + quad * 8];
#pragma unroll
      for (int nt = 0; nt < 2; ++nt)
        acc1[nt][mt] = __builtin_amdgcn_mfma_f32_16x16x32_bf16(a, bf1[nt][kt], acc1[nt][mt], 0, 0, 0);
    }
  }
  __syncthreads();  // all h reads done before aliasing S as act

#pragma unroll
  for (int nt = 0; nt < 2; ++nt) {
    int col = w * 32 + nt * 16 + l16;
#pragma unroll
    for (int mt = 0; mt < 8; ++mt)
#pragma unroll
      for (int r = 0; r < 4; ++r) {
        float v = acc1[nt][mt][r] + b1v[nt];
        v = v > 0.f ? v : 0.f;
        S[(mt * 16 + quad * 4 + r) * 264 + col] = f2bf(v);
      }
  }
  __syncthreads();

  // GEMM2: D = W2 * act^T ; wave w: out-ch tile mt2=w>>1, row half (w&1)
  const int mt2 = w >> 1;
  short8 a2[8];
#pragma unroll
  for (int kt = 0; kt < 8; ++kt)
    a2[kt] = *(const short8*)(W2b + (size_t)(mt2 * 16 + l16) * 256 + kt * 32 + quad * 8);
  float4v acc2[4] = {{0.f,0.f,0.f,0.f},{0.f,0.f,0.f,0.f},
                     {0.f,0.f,0.f,0.f},{0.f,0.f,0.f,0.f}};
#pragma unroll
  for (int kt = 0; kt < 8; ++kt) {
#pragma unroll
    for (int nt2 = 0; nt2 < 4; ++nt2) {
      int n0 = (w & 1) * 64 + nt2 * 16;
      short8 b = *(const short8*)&S[(n0 + l16) * 264 + kt * 32 + quad * 8];
      acc2[nt2] = __builtin_amdgcn_mfma_f32_16x16x32_bf16(a2[kt], b, acc2[nt2], 0, 0, 0);
    }
  }
  const float* b2p = b2 + mt2 * 16 + quad * 4;
  float b2v0 = b2p[0], b2v1 = b2p[1], b2v2 = b2p[2], b2v3 = b2p[3];
#pragma unroll
  for (int nt2 = 0; nt2 < 4; ++nt2) {
    int R = rows0 + (w & 1) * 64 + nt2 * 16 + l16;
    float m = mask[R];
    float4v out;
    out[0] = (acc2[nt2][0] + b2v0) * m;
    out[1] = (acc2[nt2][1] + b2v1) * m;
    out[2] = (acc2[nt2][2] + b2v2) * m;
    out[3] = (acc2[nt2][3] + b2v3) * m;
    *(float4v*)(y + (size_t)R * 64 + mt2 * 16 + quad * 4) = out;
  }
}

extern "C" void kernel_launch(void* const* d_in, const int* in_sizes, int n_in,
                              void* d_out, int out_size, void* d_ws, size_t ws_size,
                              hipStream_t stream) {
  (void)in_sizes; (void)n_in; (void)out_size; (void)ws_size;
  const float* x    = (const float*)d_in[0];
  const float* mask = (const float*)d_in[1];
  const float* h0   = (const float*)d_in[2];
  const float* c0   = (const float*)d_in[3];
  const float* W_ih = (const float*)d_in[4];
  const float* W_hh = (const float*)d_in[5];
  const float* b_ih = (const float*)d_in[6];
  const float* b_hh = (const float*)d_in[7];
  const float* W1   = (const float*)d_in[8];
  const float* b1   = (const float*)d_in[9];
  const float* W2   = (const float*)d_in[10];
  const float* b2   = (const float*)d_in[11];
  float* y = (float*)d_out;

  char* ws = (char*)d_ws;
  float*    exch  = (float*)ws;                          // 1 MiB slow (MALL) exchange, self-tagged
  float*    exchf = (float*)(ws + (1u << 20));           // 1 MiB fast (same-XCD L2) exchange, id-tagged
  short*    W1b   = (short*)(ws + (2u << 20));           // 128 KiB
  short*    W2b   = (short*)(ws + (2u << 20) + 131072);  // 32 KiB
  unsigned* tbl   = (unsigned*)(ws + (2u << 20) + 131072 + 32768); // 256 B XCD table
  uint16_t* hs    = (uint16_t*)(ws + (3u << 20));        // [B,T,H] bf16 = 256 MiB

  prep_kernel<<<160, 512, 0, stream>>>(W1, W2, W1b, W2b, tbl);
  lstm_kernel<<<64, 512, 0, stream>>>(x, h0, c0, W_ih, W_hh, b_ih, b_hh, exch, exchf, tbl, hs);
  mlp_kernel<<<4096, 512, 0, stream>>>(hs, W1b, b1, W2b, b2, mask, y);
}

// Round 3
// 3682.031 us; speedup vs baseline: 2.0976x; 2.0976x over previous
//
#include <hip/hip_runtime.h>
#include <stdint.h>
#include <stddef.h>

#define T_STEPS 1024
#define BATCH   512
#define HID     256
#define DIN     64

typedef __attribute__((ext_vector_type(8))) short short8;
typedef __attribute__((ext_vector_type(4))) short short4v;
typedef __attribute__((ext_vector_type(2))) short short2v;
typedef __attribute__((ext_vector_type(4))) float float4v;

static __device__ __forceinline__ short f2bf(float f) {
  union { float f; unsigned u; } v; v.f = f;
  unsigned r = (v.u + 0x7FFFu + ((v.u >> 16) & 1u)) >> 16;
  return (short)r;
}
static __device__ __forceinline__ float sigm(float x) {
  return 1.0f / (1.0f + __expf(-x));
}
static __device__ __forceinline__ float tanh_f(float x) {
  return 2.0f / (1.0f + __expf(-2.0f * x)) - 1.0f;
}

// ---------------------------------------------------------------------------
// XCD-local L2 exchange primitives. CDNA vector L1 has no atomic path, so
// atomics are ALWAYS executed in the TCC (L2). Unscoped (no sc1) atomics are
// performed at the issuing XCD's local L2 -- a coherence point shared by two
// blocks verified (XCC_ID handshake) to be on the same XCD. This avoids both
// the stale-L1 problem (R2: sc0 loads re-hit stale L1 lines) and the MALL
// round-trip (~2000cy) of agent-scope atomics.
// ---------------------------------------------------------------------------
static __device__ __forceinline__ void ast64x2_l2(unsigned long long* p,
                                                  unsigned long long v0,
                                                  unsigned long long v1) {
  asm volatile("global_atomic_swap_x2 %0, %1, off\n\t"
               "global_atomic_swap_x2 %0, %2, off offset:8"
               :: "v"(p), "v"(v0), "v"(v1) : "memory");
}
static __device__ __forceinline__ void ald64x2_l2(const unsigned long long* p,
                                                  unsigned long long& r0,
                                                  unsigned long long& r1) {
  unsigned long long z = 0;
  asm volatile("global_atomic_add_x2 %0, %2, %3, off sc0\n\t"
               "global_atomic_add_x2 %1, %2, %3, off offset:8 sc0\n\t"
               "s_waitcnt vmcnt(0)"
               : "=&v"(r0), "=&v"(r1)
               : "v"(p), "v"(z)
               : "memory");
}

// ---------------------------------------------------------------------------
// Persistent LSTM recurrence. 64 blocks = 32 batch-groups x 2 gate-halves.
// Pair exchange of h(t) per thread = 4 hidden values (16B).
//   FAST path (pair on same XCD, verified per launch): two 8B L2 atomics.
//     Word layout: w0 = [id | bf16x2], w1 = [bf16x2 | id], id = 0xC0DE0000|t
//     (exact step). Payload is the EXACT bf16 the producer puts in its own
//     A-LDS -> zero numeric divergence. Each 8B atomic is untearable; accept
//     requires BOTH ids -> no cross-word skew. Poison 0xAAAAAAAA and any
//     other-step leftover never match the expected id. Max pair skew is 1
//     step (producer of t+1 needs our t), so 2 parity buffers suffice.
//     Bounded poll guard: a visibility bug becomes an absmax fail, not hang.
//   SLOW path (cross-XCD fallback): unchanged baseline protocol (agent-scope
//     MALL atomics, fp32 words parity-tagged in mantissa bit0) -- proven.
// Freshness: prep_kernel zeroes the XCD table every launch (stream order).
// ---------------------------------------------------------------------------
__global__ __launch_bounds__(512, 2) void lstm_kernel(
    const float* __restrict__ x, const float* __restrict__ h0,
    const float* __restrict__ c0, const float* __restrict__ W_ih,
    const float* __restrict__ W_hh, const float* __restrict__ b_ih,
    const float* __restrict__ b_hh, float* __restrict__ exch,
    float* __restrict__ exchf, unsigned* __restrict__ tbl,
    uint16_t* __restrict__ hs) {
  const int tid   = threadIdx.x;
  const int blk   = blockIdx.x;
  const int group = blk & 31;
  const int half  = blk >> 5;
  const int b0    = group * 16;
  const int w     = tid >> 6;
  const int lane  = tid & 63;
  const int quad  = lane >> 4;
  const int l16   = lane & 15;
  const int partner = blk ^ 32;

  __shared__ short Alds[16 * 328];   // A = [h(256) | x(64)] bf16
  __shared__ float Glds[16 * 516];   // gate preacts fp32
  __shared__ int s_fastex;

  // ---- update-phase mapping: thread owns (urow, hh0..hh0+3) of its half
  const int urow = tid >> 5;
  const int hh0  = (tid & 31) * 4;
  const int xc   = (tid & 31) * 2;

  // exchange word pointers (widx strides by 2 between adjacent threads; each
  // thread owns u64 slots [widx, widx+1] of a 1024-u64 buffer).
  const int widx = urow * 64 + (hh0 >> 1);
  unsigned long long* sbuf[2];
  const unsigned long long* pbuf[2];
  unsigned long long* sfast[2];
  const unsigned long long* pfast[2];
#pragma unroll
  for (int bfi = 0; bfi < 2; ++bfi) {
    sbuf[bfi]  = (unsigned long long*)(exch + ((size_t)blk * 2 + bfi) * 2048) + widx;
    pbuf[bfi]  = (const unsigned long long*)(exch + ((size_t)partner * 2 + bfi) * 2048) + widx;
    sfast[bfi] = (unsigned long long*)exchf + ((size_t)blk * 2 + bfi) * 1024 + widx;
    pfast[bfi] = (const unsigned long long*)exchf + ((size_t)partner * 2 + bfi) * 1024 + widx;
  }

  // ---- XCD handshake (overlaps with weight staging below)
  if (tid == 0) {
    int xcd;
    asm volatile("s_getreg_b32 %0, hwreg(HW_REG_XCC_ID)" : "=s"(xcd));
    unsigned my = 0x5AB00000u | ((unsigned)xcd & 0xFFu);
    __hip_atomic_store(&tbl[blk], my, __ATOMIC_RELAXED, __HIP_MEMORY_SCOPE_AGENT);
    unsigned pv = 0;
    for (int g2 = 0; g2 < (1 << 16); ++g2) {
      pv = __hip_atomic_load(&tbl[partner], __ATOMIC_RELAXED, __HIP_MEMORY_SCOPE_AGENT);
      if ((pv & 0xFFFFFF00u) == 0x5AB00000u) break;
      __builtin_amdgcn_s_sleep(8);
    }
    s_fastex = (((pv & 0xFFFFFF00u) == 0x5AB00000u) &&
                ((pv & 0xFFu) == (my & 0xFFu))) ? 1 : 0;
  }

  // ---- resident weights, PERMUTED by half so register indices are static:
  // bw[0..3] = own-half h K-tiles, bw[4..7] = partner-half, bw[8..9] = x.
  short8 bw[10][4];
#pragma unroll
  for (int j = 0; j < 10; ++j) {
    int ktA = (j < 4) ? (half * 4 + j) : (j < 8) ? ((1 - half) * 4 + (j - 4)) : j;
#pragma unroll
    for (int nt = 0; nt < 4; ++nt) {
      int n_loc = w * 64 + nt * 16 + l16;          // 0..511 within block
      int gate  = n_loc >> 7;
      int hh    = n_loc & 127;
      int grow  = gate * 256 + half * 128 + hh;    // output row in 4H
      const float* src = (ktA < 8)
          ? (W_hh + (size_t)grow * 256 + ktA * 32 + quad * 8)
          : (W_ih + (size_t)grow * 64 + (ktA - 8) * 32 + quad * 8);
      short8 bv;
#pragma unroll
      for (int e = 0; e < 8; ++e) bv[e] = f2bf(src[e]);
      bw[j][nt] = bv;
    }
  }

  float bias[4][4];
  float c_reg[4];
#pragma unroll
  for (int g = 0; g < 4; ++g) {
    const float* bi = b_ih + g * 256 + half * 128 + hh0;
    const float* bh = b_hh + g * 256 + half * 128 + hh0;
#pragma unroll
    for (int r = 0; r < 4; ++r) bias[g][r] = bi[r] + bh[r];
  }
  {
    const float* c0p = c0 + (size_t)(b0 + urow) * 256 + half * 128 + hh0;
#pragma unroll
    for (int r = 0; r < 4; ++r) c_reg[r] = c0p[r];
  }

  // ---- init A-LDS: full h0 + x(0)
  {
    int c8 = (tid & 31) * 8;
    const float* hp = h0 + (size_t)(b0 + urow) * 256 + c8;
    short8 hv;
#pragma unroll
    for (int e = 0; e < 8; ++e) hv[e] = f2bf(hp[e]);
    *(short8*)&Alds[urow * 328 + c8] = hv;
    const float* xp = x + ((size_t)(b0 + urow) * T_STEPS + 0) * DIN + xc;
    short2v xv2; xv2[0] = f2bf(xp[0]); xv2[1] = f2bf(xp[1]);
    *(short2v*)&Alds[urow * 328 + 256 + xc] = xv2;
  }
  __syncthreads();
  const int fastex = s_fastex;

  const int ownbase = half * 128;
  const int pbase   = (1 - half) * 128;

  for (int t = 0; t < T_STEPS; ++t) {
    // ---- phase 1: own-half h tiles + x tiles (no exchange needed)
    float4v acc[4] = {{0.f,0.f,0.f,0.f},{0.f,0.f,0.f,0.f},
                      {0.f,0.f,0.f,0.f},{0.f,0.f,0.f,0.f}};
    int tn = (t + 1 < T_STEPS) ? (t + 1) : t;
    const float* xp = x + ((size_t)(b0 + urow) * T_STEPS + tn) * DIN + xc;
    float xa = xp[0], xb = xp[1];

#pragma unroll
    for (int j = 0; j < 4; ++j) {
      short8 a = *(const short8*)&Alds[l16 * 328 + ownbase + j * 32 + quad * 8];
#pragma unroll
      for (int nt = 0; nt < 4; ++nt)
        acc[nt] = __builtin_amdgcn_mfma_f32_16x16x32_bf16(a, bw[j][nt], acc[nt], 0, 0, 0);
    }
#pragma unroll
    for (int j = 8; j < 10; ++j) {
      short8 a = *(const short8*)&Alds[l16 * 328 + 256 + (j - 8) * 32 + quad * 8];
#pragma unroll
      for (int nt = 0; nt < 4; ++nt)
        acc[nt] = __builtin_amdgcn_mfma_f32_16x16x32_bf16(a, bw[j][nt], acc[nt], 0, 0, 0);
    }

    // ---- obtain partner's h(t-1) words (overlapped with phase 1)
    if (t > 0) {
      int buf = (t - 1) & 1;
      short4v pv4;
      if (fastex) {
        // FAST: XCD-local L2 atomic read, exact-step-id acceptance
        unsigned idw = 0xC0DE0000u + (unsigned)(t - 1);
        unsigned long long w0 = 0, w1 = 0;
        int guard = 0;
        for (;;) {
          ald64x2_l2(pfast[buf], w0, w1);
          if (((unsigned)w0 == idw) & ((unsigned)(w1 >> 32) == idw)) break;
          if (++guard > 1024) break;   // bounded: bug -> absmax fail, not hang
        }
        unsigned pay01 = (unsigned)(w0 >> 32);
        unsigned pay23 = (unsigned)w1;
        pv4[0] = (short)(pay01 & 0xFFFFu); pv4[1] = (short)(pay01 >> 16);
        pv4[2] = (short)(pay23 & 0xFFFFu); pv4[3] = (short)(pay23 >> 16);
      } else {
        // SLOW: baseline agent-scope (MALL) parity-tagged protocol
        unsigned tag = 1u ^ (((unsigned)(t - 1) >> 1) & 1u);
        const unsigned long long* p = pbuf[buf];
        unsigned long long w0, w1;
        int guard = 0;
        for (;;) {
          w0 = __hip_atomic_load(p,     __ATOMIC_RELAXED, __HIP_MEMORY_SCOPE_AGENT);
          w1 = __hip_atomic_load(p + 1, __ATOMIC_RELAXED, __HIP_MEMORY_SCOPE_AGENT);
          bool ok = (((unsigned)w0 & 1u) == tag) & ((((unsigned)(w0 >> 32)) & 1u) == tag) &
                    (((unsigned)w1 & 1u) == tag) & ((((unsigned)(w1 >> 32)) & 1u) == tag);
          if (ok) break;
          if (++guard > 4096) break;
        }
        union { unsigned u; float f; } g0, g1, g2, g3;
        g0.u = (unsigned)w0; g1.u = (unsigned)(w0 >> 32);
        g2.u = (unsigned)w1; g3.u = (unsigned)(w1 >> 32);
        pv4[0] = f2bf(g0.f); pv4[1] = f2bf(g1.f);
        pv4[2] = f2bf(g2.f); pv4[3] = f2bf(g3.f);
      }
      *(short4v*)&Alds[urow * 328 + pbase + hh0] = pv4;
    }
    __syncthreads();   // partner region ready

    // ---- phase 2: partner-half h tiles
#pragma unroll
    for (int j = 4; j < 8; ++j) {
      short8 a = *(const short8*)&Alds[l16 * 328 + pbase + (j - 4) * 32 + quad * 8];
#pragma unroll
      for (int nt = 0; nt < 4; ++nt)
        acc[nt] = __builtin_amdgcn_mfma_f32_16x16x32_bf16(a, bw[j][nt], acc[nt], 0, 0, 0);
    }
    // preacts -> G-LDS (D layout: col=l16, row=quad*4+r)
#pragma unroll
    for (int nt = 0; nt < 4; ++nt) {
      int col = w * 64 + nt * 16 + l16;
#pragma unroll
      for (int r = 0; r < 4; ++r)
        Glds[(quad * 4 + r) * 516 + col] = acc[nt][r];
    }
    __syncthreads();   // gates ready; A-LDS reads done

    // ---- cell update (fp32 state in regs)
    float4v ip = *(const float4v*)&Glds[urow * 516 + 0   + hh0];
    float4v fp = *(const float4v*)&Glds[urow * 516 + 128 + hh0];
    float4v gp = *(const float4v*)&Glds[urow * 516 + 256 + hh0];
    float4v op = *(const float4v*)&Glds[urow * 516 + 384 + hh0];
    float hf[4];
    short hb[4];
#pragma unroll
    for (int r = 0; r < 4; ++r) {
      float iv = sigm(ip[r] + bias[0][r]);
      float fv = sigm(fp[r] + bias[1][r]);
      float gv = tanh_f(gp[r] + bias[2][r]);
      float ov = sigm(op[r] + bias[3][r]);
      float cv = fv * c_reg[r] + iv * gv;
      c_reg[r] = cv;
      hf[r] = ov * tanh_f(cv);
      hb[r] = f2bf(hf[r]);
    }
    // exchange store FIRST (earliest visibility to partner)
    {
      int buf = t & 1;
      if (fastex) {
        unsigned idw = 0xC0DE0000u + (unsigned)t;
        unsigned pay01 = (unsigned)(unsigned short)hb[0]
                       | ((unsigned)(unsigned short)hb[1] << 16);
        unsigned pay23 = (unsigned)(unsigned short)hb[2]
                       | ((unsigned)(unsigned short)hb[3] << 16);
        unsigned long long w0 = (unsigned long long)idw
                              | ((unsigned long long)pay01 << 32);
        unsigned long long w1 = (unsigned long long)pay23
                              | ((unsigned long long)idw << 32);
        ast64x2_l2(sfast[buf], w0, w1);
      } else {
        unsigned tag = 1u ^ (((unsigned)t >> 1) & 1u);
        union { float f; unsigned u; } u0, u1, u2, u3;
        u0.f = hf[0]; u1.f = hf[1]; u2.f = hf[2]; u3.f = hf[3];
        unsigned long long w0 = (unsigned long long)((u0.u & ~1u) | tag)
                              | ((unsigned long long)((u1.u & ~1u) | tag) << 32);
        unsigned long long w1 = (unsigned long long)((u2.u & ~1u) | tag)
                              | ((unsigned long long)((u3.u & ~1u) | tag) << 32);
        __hip_atomic_store(sbuf[buf],     w0, __ATOMIC_RELAXED, __HIP_MEMORY_SCOPE_AGENT);
        __hip_atomic_store(sbuf[buf] + 1, w1, __ATOMIC_RELAXED, __HIP_MEMORY_SCOPE_AGENT);
      }
    }
    // own half -> A-LDS
    short4v hv4; hv4[0] = hb[0]; hv4[1] = hb[1]; hv4[2] = hb[2]; hv4[3] = hb[3];
    *(short4v*)&Alds[urow * 328 + ownbase + hh0] = hv4;
    // hs for MLP: plain cached store (kernel boundary provides visibility)
    *(short4v*)(hs + ((size_t)(b0 + urow) * T_STEPS + t) * HID + ownbase + hh0) = hv4;
    // x(t+1) -> A-LDS
    short2v xv2; xv2[0] = f2bf(xa); xv2[1] = f2bf(xb);
    *(short2v*)&Alds[urow * 328 + 256 + xc] = xv2;
    __syncthreads();   // own half + x ready for next phase 1
  }
}

// ---------------------------------------------------------------------------
// One-time fp32 -> bf16 conversion of MLP weights into workspace, plus
// zeroing of the XCD pairing table (fresh, poison-proof table every launch
// via stream ordering).
// ---------------------------------------------------------------------------
__global__ void prep_kernel(const float* __restrict__ W1, const float* __restrict__ W2,
                            short* __restrict__ W1b, short* __restrict__ W2b,
                            unsigned* __restrict__ tbl) {
  int i = blockIdx.x * 512 + threadIdx.x;   // 160*512 = 81920 = 65536 + 16384
  if (i < 64)
    __hip_atomic_store(&tbl[i], 0u, __ATOMIC_RELAXED, __HIP_MEMORY_SCOPE_AGENT);
  if (i < 65536) W1b[i] = f2bf(W1[i]);
  else           W2b[i - 65536] = f2bf(W2[i - 65536]);
}

// ---------------------------------------------------------------------------
// Fused MLP head: y = relu(hs @ W1^T + b1) @ W2^T + b2, * mask.
// 4096 blocks x 128 rows (weights amortized over 2x more rows than R1,
// and loaded as bf16 -> 4x less weight traffic per row).
// ---------------------------------------------------------------------------
__global__ __launch_bounds__(512, 2) void mlp_kernel(
    const uint16_t* __restrict__ hs, const short* __restrict__ W1b,
    const float* __restrict__ b1, const short* __restrict__ W2b,
    const float* __restrict__ b2, const float* __restrict__ mask,
    float* __restrict__ y) {
  const int tid   = threadIdx.x;
  const int rows0 = blockIdx.x * 128;
  const int w     = tid >> 6;
  const int lane  = tid & 63;
  const int quad  = lane >> 4;
  const int l16   = lane & 15;

  __shared__ short S[128 * 264];  // h tile, later aliased as act tile

  // stage h tile [128,256] bf16
#pragma unroll
  for (int kk = 0; kk < 8; ++kk) {
    int c   = tid + kk * 512;
    int row = c >> 5;
    int off = (c & 31) * 8;
    *(short8*)&S[row * 264 + off] =
        *(const short8*)(hs + (size_t)(rows0 + row) * HID + off);
  }

  // W1 B-fragments; wave w owns hidden cols [w*32, w*32+32)
  short8 bf1[2][8];
  float  b1v[2];
#pragma unroll
  for (int nt = 0; nt < 2; ++nt) {
    int n = w * 32 + nt * 16 + l16;
    b1v[nt] = b1[n];
#pragma unroll
    for (int kt = 0; kt < 8; ++kt)
      bf1[nt][kt] = *(const short8*)(W1b + (size_t)n * 256 + kt * 32 + quad * 8);
  }
  __syncthreads();

  // GEMM1: act = relu(h @ W1^T + b1), 8 M-tiles
  float4v acc1[2][8];
#pragma unroll
  for (int nt = 0; nt < 2; ++nt)
#pragma unroll
    for (int mt = 0; mt < 8; ++mt) acc1[nt][mt] = (float4v){0.f,0.f,0.f,0.f};
#pragma unroll
  for (int kt = 0; kt < 8; ++kt) {
#pragma unroll
    for (int mt = 0; mt < 8; ++mt) {
      short8 a = *(const short8*)&S[(mt * 16 + l16) * 264 + kt * 32 + quad * 8];
#pragma unroll
      for (int nt = 0; nt < 2; ++nt)
        acc1[nt][mt] = __builtin_amdgcn_mfma_f32_16x16x32_bf16(a, bf1[nt][kt], acc1[nt][mt], 0, 0, 0);
    }
  }
  __syncthreads();  // all h reads done before aliasing S as act

#pragma unroll
  for (int nt = 0; nt < 2; ++nt) {
    int col = w * 32 + nt * 16 + l16;
#pragma unroll
    for (int mt = 0; mt < 8; ++mt)
#pragma unroll
      for (int r = 0; r < 4; ++r) {
        float v = acc1[nt][mt][r] + b1v[nt];
        v = v > 0.f ? v : 0.f;
        S[(mt * 16 + quad * 4 + r) * 264 + col] = f2bf(v);
      }
  }
  __syncthreads();

  // GEMM2: D = W2 * act^T ; wave w: out-ch tile mt2=w>>1, row half (w&1)
  const int mt2 = w >> 1;
  short8 a2[8];
#pragma unroll
  for (int kt = 0; kt < 8; ++kt)
    a2[kt] = *(const short8*)(W2b + (size_t)(mt2 * 16 + l16) * 256 + kt * 32 + quad * 8);
  float4v acc2[4] = {{0.f,0.f,0.f,0.f},{0.f,0.f,0.f,0.f},
                     {0.f,0.f,0.f,0.f},{0.f,0.f,0.f,0.f}};
#pragma unroll
  for (int kt = 0; kt < 8; ++kt) {
#pragma unroll
    for (int nt2 = 0; nt2 < 4; ++nt2) {
      int n0 = (w & 1) * 64 + nt2 * 16;
      short8 b = *(const short8*)&S[(n0 + l16) * 264 + kt * 32 + quad * 8];
      acc2[nt2] = __builtin_amdgcn_mfma_f32_16x16x32_bf16(a2[kt], b, acc2[nt2], 0, 0, 0);
    }
  }
  const float* b2p = b2 + mt2 * 16 + quad * 4;
  float b2v0 = b2p[0], b2v1 = b2p[1], b2v2 = b2p[2], b2v3 = b2p[3];
#pragma unroll
  for (int nt2 = 0; nt2 < 4; ++nt2) {
    int R = rows0 + (w & 1) * 64 + nt2 * 16 + l16;
    float m = mask[R];
    float4v out;
    out[0] = (acc2[nt2][0] + b2v0) * m;
    out[1] = (acc2[nt2][1] + b2v1) * m;
    out[2] = (acc2[nt2][2] + b2v2) * m;
    out[3] = (acc2[nt2][3] + b2v3) * m;
    *(float4v*)(y + (size_t)R * 64 + mt2 * 16 + quad * 4) = out;
  }
}

extern "C" void kernel_launch(void* const* d_in, const int* in_sizes, int n_in,
                              void* d_out, int out_size, void* d_ws, size_t ws_size,
                              hipStream_t stream) {
  (void)in_sizes; (void)n_in; (void)out_size; (void)ws_size;
  const float* x    = (const float*)d_in[0];
  const float* mask = (const float*)d_in[1];
  const float* h0   = (const float*)d_in[2];
  const float* c0   = (const float*)d_in[3];
  const float* W_ih = (const float*)d_in[4];
  const float* W_hh = (const float*)d_in[5];
  const float* b_ih = (const float*)d_in[6];
  const float* b_hh = (const float*)d_in[7];
  const float* W1   = (const float*)d_in[8];
  const float* b1   = (const float*)d_in[9];
  const float* W2   = (const float*)d_in[10];
  const float* b2   = (const float*)d_in[11];
  float* y = (float*)d_out;

  char* ws = (char*)d_ws;
  float*    exch  = (float*)ws;                          // 1 MiB slow (MALL) exchange, parity-tagged
  float*    exchf = (float*)(ws + (1u << 20));           // 1 MiB fast (XCD-local L2) exchange, id-tagged
  short*    W1b   = (short*)(ws + (2u << 20));           // 128 KiB
  short*    W2b   = (short*)(ws + (2u << 20) + 131072);  // 32 KiB
  unsigned* tbl   = (unsigned*)(ws + (2u << 20) + 131072 + 32768); // 256 B XCD table
  uint16_t* hs    = (uint16_t*)(ws + (3u << 20));        // [B,T,H] bf16 = 256 MiB

  prep_kernel<<<160, 512, 0, stream>>>(W1, W2, W1b, W2b, tbl);
  lstm_kernel<<<64, 512, 0, stream>>>(x, h0, c0, W_ih, W_hh, b_ih, b_hh, exch, exchf, tbl, hs);
  mlp_kernel<<<4096, 512, 0, stream>>>(hs, W1b, b1, W2b, b2, mask, y);
}

// Round 4
// 3403.779 us; speedup vs baseline: 2.2691x; 1.0817x over previous
//
#include <hip/hip_runtime.h>
#include <stdint.h>
#include <stddef.h>

#define T_STEPS 1024
#define BATCH   512
#define HID     256
#define DIN     64

typedef __attribute__((ext_vector_type(8))) short short8;
typedef __attribute__((ext_vector_type(4))) short short4v;
typedef __attribute__((ext_vector_type(2))) short short2v;
typedef __attribute__((ext_vector_type(4))) float float4v;

static __device__ __forceinline__ short f2bf(float f) {
  union { float f; unsigned u; } v; v.f = f;
  unsigned r = (v.u + 0x7FFFu + ((v.u >> 16) & 1u)) >> 16;
  return (short)r;
}
static __device__ __forceinline__ float sigm(float x) {
  return 1.0f / (1.0f + __expf(-x));
}
static __device__ __forceinline__ float tanh_f(float x) {
  return 2.0f / (1.0f + __expf(-2.0f * x)) - 1.0f;
}

// ---------------------------------------------------------------------------
// Exchange primitives — UNCHANGED from the R3-validated version.
// ---------------------------------------------------------------------------
static __device__ __forceinline__ void ast64x2_l2(unsigned long long* p,
                                                  unsigned long long v0,
                                                  unsigned long long v1) {
  asm volatile("global_atomic_swap_x2 %0, %1, off\n\t"
               "global_atomic_swap_x2 %0, %2, off offset:8"
               :: "v"(p), "v"(v0), "v"(v1) : "memory");
}
static __device__ __forceinline__ void ald64x2_l2(const unsigned long long* p,
                                                  unsigned long long& r0,
                                                  unsigned long long& r1) {
  unsigned long long z = 0;
  asm volatile("global_atomic_add_x2 %0, %2, %3, off sc0\n\t"
               "global_atomic_add_x2 %1, %2, %3, off offset:8 sc0\n\t"
               "s_waitcnt vmcnt(0)"
               : "=&v"(r0), "=&v"(r1)
               : "v"(p), "v"(z)
               : "memory");
}

// ---------------------------------------------------------------------------
// Persistent LSTM recurrence. 64 blocks = 32 batch-groups x 2 gate-halves.
//
// GATE-MAJOR accumulator mapping (this round's change): wave w's 4 output
// col-tiles are cols {g*128 + w*16 + l16, g=0..3} -- the 4 GATES of hidden
// unit hh = w*16 + l16. So after phase 2, each thread holds i,f,g,o preacts
// for (rows quad*4+r, its hh) ENTIRELY IN REGISTERS:
//   - the fp32 Glds transpose round-trip is deleted (16 ds_write + 4
//     ds_read_b128 + 1 barrier per step, and its 2.1e7 bank conflicts),
//   - barriers per step: 3 -> 2,
//   - cell update is register-only; h written back as 4 column ds_write_b16
//     (region-disjoint from partner writes -> no WAR, no double buffer).
// hs store deferred one step: h(t-1) re-read row-major from A-LDS during
// step t's phase 1 (read-read concurrency), keeping global coalescing.
//
// Exchange protocol (fast same-XCD L2 atomics + agent-scope MALL fallback,
// XCC_ID handshake, exact-step-id 16B words, bounded guards): byte-for-byte
// the R3-validated logic; only the consumer's LDS write pattern changed to
// the column form.
// ---------------------------------------------------------------------------
__global__ __launch_bounds__(512, 2) void lstm_kernel(
    const float* __restrict__ x, const float* __restrict__ h0,
    const float* __restrict__ c0, const float* __restrict__ W_ih,
    const float* __restrict__ W_hh, const float* __restrict__ b_ih,
    const float* __restrict__ b_hh, float* __restrict__ exch,
    float* __restrict__ exchf, unsigned* __restrict__ tbl,
    uint16_t* __restrict__ hs) {
  const int tid   = threadIdx.x;
  const int blk   = blockIdx.x;
  const int group = blk & 31;
  const int half  = blk >> 5;
  const int b0    = group * 16;
  const int w     = tid >> 6;
  const int lane  = tid & 63;
  const int quad  = lane >> 4;
  const int l16   = lane & 15;
  const int w16l  = w * 16 + l16;          // hh within half, 0..127
  const int partner = blk ^ 32;

  __shared__ short Alds[16 * 328];   // A = [h(256) | x(64)] bf16
  __shared__ int s_fastex;

  // ---- legacy row-major mapping (used for x staging + hs readback)
  const int urow = tid >> 5;
  const int hh0  = (tid & 31) * 4;
  const int xc   = (tid & 31) * 2;

  // exchange slots: thread owns 16B at u64 offset 2*tid of each 8KB buffer
  const int widx = tid * 2;
  unsigned long long* sbuf[2];
  const unsigned long long* pbuf[2];
  unsigned long long* sfast[2];
  const unsigned long long* pfast[2];
#pragma unroll
  for (int bfi = 0; bfi < 2; ++bfi) {
    sbuf[bfi]  = (unsigned long long*)(exch + ((size_t)blk * 2 + bfi) * 2048) + widx;
    pbuf[bfi]  = (const unsigned long long*)(exch + ((size_t)partner * 2 + bfi) * 2048) + widx;
    sfast[bfi] = (unsigned long long*)exchf + ((size_t)blk * 2 + bfi) * 1024 + widx;
    pfast[bfi] = (const unsigned long long*)exchf + ((size_t)partner * 2 + bfi) * 1024 + widx;
  }

  // ---- XCD handshake (overlaps with weight staging below)
  if (tid == 0) {
    int xcd;
    asm volatile("s_getreg_b32 %0, hwreg(HW_REG_XCC_ID)" : "=s"(xcd));
    unsigned my = 0x5AB00000u | ((unsigned)xcd & 0xFFu);
    __hip_atomic_store(&tbl[blk], my, __ATOMIC_RELAXED, __HIP_MEMORY_SCOPE_AGENT);
    unsigned pv = 0;
    for (int g2 = 0; g2 < (1 << 16); ++g2) {
      pv = __hip_atomic_load(&tbl[partner], __ATOMIC_RELAXED, __HIP_MEMORY_SCOPE_AGENT);
      if ((pv & 0xFFFFFF00u) == 0x5AB00000u) break;
      __builtin_amdgcn_s_sleep(8);
    }
    s_fastex = (((pv & 0xFFFFFF00u) == 0x5AB00000u) &&
                ((pv & 0xFFu) == (my & 0xFFu))) ? 1 : 0;
  }

  // ---- resident weights, gate-major cols, PERMUTED by half:
  // bw[0..3] = own-half h K-tiles, bw[4..7] = partner-half, bw[8..9] = x.
  // bw[j][g] covers output col-tile starting at g*128 + w*16.
  short8 bw[10][4];
#pragma unroll
  for (int j = 0; j < 10; ++j) {
    int ktA = (j < 4) ? (half * 4 + j) : (j < 8) ? ((1 - half) * 4 + (j - 4)) : j;
#pragma unroll
    for (int g = 0; g < 4; ++g) {
      int n_loc = g * 128 + w16l;                  // 0..511 within block
      int grow  = g * 256 + half * 128 + w16l;     // output row in 4H
      const float* src = (ktA < 8)
          ? (W_hh + (size_t)grow * 256 + ktA * 32 + quad * 8)
          : (W_ih + (size_t)grow * 64 + (ktA - 8) * 32 + quad * 8);
      (void)n_loc;
      short8 bv;
#pragma unroll
      for (int e = 0; e < 8; ++e) bv[e] = f2bf(src[e]);
      bw[j][g] = bv;
    }
  }

  // ---- update-phase state: this thread owns (rows quad*4+r, hh = w16l)
  const int hh_abs = half * 128 + w16l;            // absolute hidden idx
  float bias_g[4];
#pragma unroll
  for (int g = 0; g < 4; ++g)
    bias_g[g] = b_ih[g * 256 + hh_abs] + b_hh[g * 256 + hh_abs];
  float c_reg[4];
#pragma unroll
  for (int r = 0; r < 4; ++r)
    c_reg[r] = c0[(size_t)(b0 + quad * 4 + r) * 256 + hh_abs];

  // ---- init A-LDS: full h0 + x(0)
  {
    int c8 = (tid & 31) * 8;
    const float* hp = h0 + (size_t)(b0 + urow) * 256 + c8;
    short8 hv;
#pragma unroll
    for (int e = 0; e < 8; ++e) hv[e] = f2bf(hp[e]);
    *(short8*)&Alds[urow * 328 + c8] = hv;
    const float* xp = x + ((size_t)(b0 + urow) * T_STEPS + 0) * DIN + xc;
    short2v xv2; xv2[0] = f2bf(xp[0]); xv2[1] = f2bf(xp[1]);
    *(short2v*)&Alds[urow * 328 + 256 + xc] = xv2;
  }
  __syncthreads();
  const int fastex = s_fastex;

  const int ownbase = half * 128;
  const int pbase   = (1 - half) * 128;

  for (int t = 0; t < T_STEPS; ++t) {
    // ---- phase 1: own-half h tiles + x tiles (no exchange needed)
    float4v acc[4] = {{0.f,0.f,0.f,0.f},{0.f,0.f,0.f,0.f},
                      {0.f,0.f,0.f,0.f},{0.f,0.f,0.f,0.f}};
    int tn = (t + 1 < T_STEPS) ? (t + 1) : t;
    const float* xp = x + ((size_t)(b0 + urow) * T_STEPS + tn) * DIN + xc;
    float xa = xp[0], xb = xp[1];

#pragma unroll
    for (int j = 0; j < 4; ++j) {
      short8 a = *(const short8*)&Alds[l16 * 328 + ownbase + j * 32 + quad * 8];
#pragma unroll
      for (int g = 0; g < 4; ++g)
        acc[g] = __builtin_amdgcn_mfma_f32_16x16x32_bf16(a, bw[j][g], acc[g], 0, 0, 0);
    }
#pragma unroll
    for (int j = 8; j < 10; ++j) {
      short8 a = *(const short8*)&Alds[l16 * 328 + 256 + (j - 8) * 32 + quad * 8];
#pragma unroll
      for (int g = 0; g < 4; ++g)
        acc[g] = __builtin_amdgcn_mfma_f32_16x16x32_bf16(a, bw[j][g], acc[g], 0, 0, 0);
    }

    // ---- deferred hs store: h(t-1) from A-LDS (row-major, coalesced);
    // read-read concurrent with phase-1 fragment reads, store is
    // fire-and-forget.
    if (t > 0) {
      short4v hv = *(const short4v*)&Alds[urow * 328 + ownbase + hh0];
      *(short4v*)(hs + ((size_t)(b0 + urow) * T_STEPS + (t - 1)) * HID + ownbase + hh0) = hv;
    }

    // ---- obtain partner's h(t-1) words (overlapped with phase 1)
    if (t > 0) {
      int buf = (t - 1) & 1;
      short4v pv4;
      if (fastex) {
        // FAST: XCD-local L2 atomic read, exact-step-id acceptance
        unsigned idw = 0xC0DE0000u + (unsigned)(t - 1);
        unsigned long long w0 = 0, w1 = 0;
        int guard = 0;
        for (;;) {
          ald64x2_l2(pfast[buf], w0, w1);
          if (((unsigned)w0 == idw) & ((unsigned)(w1 >> 32) == idw)) break;
          if (++guard > 1024) break;   // bounded: bug -> absmax fail, not hang
        }
        unsigned pay01 = (unsigned)(w0 >> 32);
        unsigned pay23 = (unsigned)w1;
        pv4[0] = (short)(pay01 & 0xFFFFu); pv4[1] = (short)(pay01 >> 16);
        pv4[2] = (short)(pay23 & 0xFFFFu); pv4[3] = (short)(pay23 >> 16);
      } else {
        // SLOW: baseline agent-scope (MALL) parity-tagged protocol
        unsigned tag = 1u ^ (((unsigned)(t - 1) >> 1) & 1u);
        const unsigned long long* p = pbuf[buf];
        unsigned long long w0, w1;
        int guard = 0;
        for (;;) {
          w0 = __hip_atomic_load(p,     __ATOMIC_RELAXED, __HIP_MEMORY_SCOPE_AGENT);
          w1 = __hip_atomic_load(p + 1, __ATOMIC_RELAXED, __HIP_MEMORY_SCOPE_AGENT);
          bool ok = (((unsigned)w0 & 1u) == tag) & ((((unsigned)(w0 >> 32)) & 1u) == tag) &
                    (((unsigned)w1 & 1u) == tag) & ((((unsigned)(w1 >> 32)) & 1u) == tag);
          if (ok) break;
          if (++guard > 4096) break;
        }
        union { unsigned u; float f; } g0, g1, g2, g3;
        g0.u = (unsigned)w0; g1.u = (unsigned)(w0 >> 32);
        g2.u = (unsigned)w1; g3.u = (unsigned)(w1 >> 32);
        pv4[0] = f2bf(g0.f); pv4[1] = f2bf(g1.f);
        pv4[2] = f2bf(g2.f); pv4[3] = f2bf(g3.f);
      }
      // column write: partner h values (rows quad*4+r, col w16l)
#pragma unroll
      for (int r = 0; r < 4; ++r)
        Alds[(quad * 4 + r) * 328 + pbase + w16l] = pv4[r];
    }
    __syncthreads();   // partner region ready

    // ---- phase 2: partner-half h tiles
#pragma unroll
    for (int j = 4; j < 8; ++j) {
      short8 a = *(const short8*)&Alds[l16 * 328 + pbase + (j - 4) * 32 + quad * 8];
#pragma unroll
      for (int g = 0; g < 4; ++g)
        acc[g] = __builtin_amdgcn_mfma_f32_16x16x32_bf16(a, bw[j][g], acc[g], 0, 0, 0);
    }

    // ---- cell update: gates are IN REGISTERS (acc[g][r] = gate g preact
    // for row quad*4+r, hh w16l). No LDS round-trip, no extra barrier.
    float hf[4];
    short hb[4];
#pragma unroll
    for (int r = 0; r < 4; ++r) {
      float iv = sigm(acc[0][r] + bias_g[0]);
      float fv = sigm(acc[1][r] + bias_g[1]);
      float gv = tanh_f(acc[2][r] + bias_g[2]);
      float ov = sigm(acc[3][r] + bias_g[3]);
      float cv = fv * c_reg[r] + iv * gv;
      c_reg[r] = cv;
      hf[r] = ov * tanh_f(cv);
      hb[r] = f2bf(hf[r]);
    }
    // exchange store FIRST (earliest visibility to partner)
    {
      int buf = t & 1;
      if (fastex) {
        unsigned idw = 0xC0DE0000u + (unsigned)t;
        unsigned pay01 = (unsigned)(unsigned short)hb[0]
                       | ((unsigned)(unsigned short)hb[1] << 16);
        unsigned pay23 = (unsigned)(unsigned short)hb[2]
                       | ((unsigned)(unsigned short)hb[3] << 16);
        unsigned long long w0 = (unsigned long long)idw
                              | ((unsigned long long)pay01 << 32);
        unsigned long long w1 = (unsigned long long)pay23
                              | ((unsigned long long)idw << 32);
        ast64x2_l2(sfast[buf], w0, w1);
      } else {
        unsigned tag = 1u ^ (((unsigned)t >> 1) & 1u);
        union { float f; unsigned u; } u0, u1, u2, u3;
        u0.f = hf[0]; u1.f = hf[1]; u2.f = hf[2]; u3.f = hf[3];
        unsigned long long w0 = (unsigned long long)((u0.u & ~1u) | tag)
                              | ((unsigned long long)((u1.u & ~1u) | tag) << 32);
        unsigned long long w1 = (unsigned long long)((u2.u & ~1u) | tag)
                              | ((unsigned long long)((u3.u & ~1u) | tag) << 32);
        __hip_atomic_store(sbuf[buf],     w0, __ATOMIC_RELAXED, __HIP_MEMORY_SCOPE_AGENT);
        __hip_atomic_store(sbuf[buf] + 1, w1, __ATOMIC_RELAXED, __HIP_MEMORY_SCOPE_AGENT);
      }
    }
    // own half -> A-LDS (column write; disjoint from pbase and x regions)
#pragma unroll
    for (int r = 0; r < 4; ++r)
      Alds[(quad * 4 + r) * 328 + ownbase + w16l] = hb[r];
    // x(t+1) -> A-LDS
    short2v xv2; xv2[0] = f2bf(xa); xv2[1] = f2bf(xb);
    *(short2v*)&Alds[urow * 328 + 256 + xc] = xv2;
    __syncthreads();   // own half + x ready for next phase 1
  }

  // ---- epilogue: hs for the final step (A-LDS own half holds h(T-1))
  {
    short4v hv = *(const short4v*)&Alds[urow * 328 + ownbase + hh0];
    *(short4v*)(hs + ((size_t)(b0 + urow) * T_STEPS + (T_STEPS - 1)) * HID + ownbase + hh0) = hv;
  }
}

// ---------------------------------------------------------------------------
// One-time fp32 -> bf16 conversion of MLP weights into workspace, plus
// zeroing of the XCD pairing table (fresh, poison-proof table every launch
// via stream ordering).
// ---------------------------------------------------------------------------
__global__ void prep_kernel(const float* __restrict__ W1, const float* __restrict__ W2,
                            short* __restrict__ W1b, short* __restrict__ W2b,
                            unsigned* __restrict__ tbl) {
  int i = blockIdx.x * 512 + threadIdx.x;   // 160*512 = 81920 = 65536 + 16384
  if (i < 64)
    __hip_atomic_store(&tbl[i], 0u, __ATOMIC_RELAXED, __HIP_MEMORY_SCOPE_AGENT);
  if (i < 65536) W1b[i] = f2bf(W1[i]);
  else           W2b[i - 65536] = f2bf(W2[i - 65536]);
}

// ---------------------------------------------------------------------------
// Fused MLP head: y = relu(hs @ W1^T + b1) @ W2^T + b2, * mask.
// 4096 blocks x 128 rows (weights amortized over 2x more rows than R1,
// and loaded as bf16 -> 4x less weight traffic per row).
// ---------------------------------------------------------------------------
__global__ __launch_bounds__(512, 2) void mlp_kernel(
    const uint16_t* __restrict__ hs, const short* __restrict__ W1b,
    const float* __restrict__ b1, const short* __restrict__ W2b,
    const float* __restrict__ b2, const float* __restrict__ mask,
    float* __restrict__ y) {
  const int tid   = threadIdx.x;
  const int rows0 = blockIdx.x * 128;
  const int w     = tid >> 6;
  const int lane  = tid & 63;
  const int quad  = lane >> 4;
  const int l16   = lane & 15;

  __shared__ short S[128 * 264];  // h tile, later aliased as act tile

  // stage h tile [128,256] bf16
#pragma unroll
  for (int kk = 0; kk < 8; ++kk) {
    int c   = tid + kk * 512;
    int row = c >> 5;
    int off = (c & 31) * 8;
    *(short8*)&S[row * 264 + off] =
        *(const short8*)(hs + (size_t)(rows0 + row) * HID + off);
  }

  // W1 B-fragments; wave w owns hidden cols [w*32, w*32+32)
  short8 bf1[2][8];
  float  b1v[2];
#pragma unroll
  for (int nt = 0; nt < 2; ++nt) {
    int n = w * 32 + nt * 16 + l16;
    b1v[nt] = b1[n];
#pragma unroll
    for (int kt = 0; kt < 8; ++kt)
      bf1[nt][kt] = *(const short8*)(W1b + (size_t)n * 256 + kt * 32 + quad * 8);
  }
  __syncthreads();

  // GEMM1: act = relu(h @ W1^T + b1), 8 M-tiles
  float4v acc1[2][8];
#pragma unroll
  for (int nt = 0; nt < 2; ++nt)
#pragma unroll
    for (int mt = 0; mt < 8; ++mt) acc1[nt][mt] = (float4v){0.f,0.f,0.f,0.f};
#pragma unroll
  for (int kt = 0; kt < 8; ++kt) {
#pragma unroll
    for (int mt = 0; mt < 8; ++mt) {
      short8 a = *(const short8*)&S[(mt * 16 + l16) * 264 + kt * 32 + quad * 8];
#pragma unroll
      for (int nt = 0; nt < 2; ++nt)
        acc1[nt][mt] = __builtin_amdgcn_mfma_f32_16x16x32_bf16(a, bf1[nt][kt], acc1[nt][mt], 0, 0, 0);
    }
  }
  __syncthreads();  // all h reads done before aliasing S as act

#pragma unroll
  for (int nt = 0; nt < 2; ++nt) {
    int col = w * 32 + nt * 16 + l16;
#pragma unroll
    for (int mt = 0; mt < 8; ++mt)
#pragma unroll
      for (int r = 0; r < 4; ++r) {
        float v = acc1[nt][mt][r] + b1v[nt];
        v = v > 0.f ? v : 0.f;
        S[(mt * 16 + quad * 4 + r) * 264 + col] = f2bf(v);
      }
  }
  __syncthreads();

  // GEMM2: D = W2 * act^T ; wave w: out-ch tile mt2=w>>1, row half (w&1)
  const int mt2 = w >> 1;
  short8 a2[8];
#pragma unroll
  for (int kt = 0; kt < 8; ++kt)
    a2[kt] = *(const short8*)(W2b + (size_t)(mt2 * 16 + l16) * 256 + kt * 32 + quad * 8);
  float4v acc2[4] = {{0.f,0.f,0.f,0.f},{0.f,0.f,0.f,0.f},
                     {0.f,0.f,0.f,0.f},{0.f,0.f,0.f,0.f}};
#pragma unroll
  for (int kt = 0; kt < 8; ++kt) {
#pragma unroll
    for (int nt2 = 0; nt2 < 4; ++nt2) {
      int n0 = (w & 1) * 64 + nt2 * 16;
      short8 b = *(const short8*)&S[(n0 + l16) * 264 + kt * 32 + quad * 8];
      acc2[nt2] = __builtin_amdgcn_mfma_f32_16x16x32_bf16(a2[kt], b, acc2[nt2], 0, 0, 0);
    }
  }
  const float* b2p = b2 + mt2 * 16 + quad * 4;
  float b2v0 = b2p[0], b2v1 = b2p[1], b2v2 = b2p[2], b2v3 = b2p[3];
#pragma unroll
  for (int nt2 = 0; nt2 < 4; ++nt2) {
    int R = rows0 + (w & 1) * 64 + nt2 * 16 + l16;
    float m = mask[R];
    float4v out;
    out[0] = (acc2[nt2][0] + b2v0) * m;
    out[1] = (acc2[nt2][1] + b2v1) * m;
    out[2] = (acc2[nt2][2] + b2v2) * m;
    out[3] = (acc2[nt2][3] + b2v3) * m;
    *(float4v*)(y + (size_t)R * 64 + mt2 * 16 + quad * 4) = out;
  }
}

extern "C" void kernel_launch(void* const* d_in, const int* in_sizes, int n_in,
                              void* d_out, int out_size, void* d_ws, size_t ws_size,
                              hipStream_t stream) {
  (void)in_sizes; (void)n_in; (void)out_size; (void)ws_size;
  const float* x    = (const float*)d_in[0];
  const float* mask = (const float*)d_in[1];
  const float* h0   = (const float*)d_in[2];
  const float* c0   = (const float*)d_in[3];
  const float* W_ih = (const float*)d_in[4];
  const float* W_hh = (const float*)d_in[5];
  const float* b_ih = (const float*)d_in[6];
  const float* b_hh = (const float*)d_in[7];
  const float* W1   = (const float*)d_in[8];
  const float* b1   = (const float*)d_in[9];
  const float* W2   = (const float*)d_in[10];
  const float* b2   = (const float*)d_in[11];
  float* y = (float*)d_out;

  char* ws = (char*)d_ws;
  float*    exch  = (float*)ws;                          // 1 MiB slow (MALL) exchange, parity-tagged
  float*    exchf = (float*)(ws + (1u << 20));           // 1 MiB fast (XCD-local L2) exchange, id-tagged
  short*    W1b   = (short*)(ws + (2u << 20));           // 128 KiB
  short*    W2b   = (short*)(ws + (2u << 20) + 131072);  // 32 KiB
  unsigned* tbl   = (unsigned*)(ws + (2u << 20) + 131072 + 32768); // 256 B XCD table
  uint16_t* hs    = (uint16_t*)(ws + (3u << 20));        // [B,T,H] bf16 = 256 MiB

  prep_kernel<<<160, 512, 0, stream>>>(W1, W2, W1b, W2b, tbl);
  lstm_kernel<<<64, 512, 0, stream>>>(x, h0, c0, W_ih, W_hh, b_ih, b_hh, exch, exchf, tbl, hs);
  mlp_kernel<<<4096, 512, 0, stream>>>(hs, W1b, b1, W2b, b2, mask, y);
}